// Round 15
// baseline (303.285 us; speedup 1.0000x reference)
//
#include <hip/hip_runtime.h>
#include <hip/hip_bf16.h>
#include <cfloat>

#define NTOK 4096
#define D_ 1024
#define DICT_ 16384
#define TOPK 8
#define NCAND 12
#define NBLKSEL 12
#define LN_EPS 1e-5f

typedef __attribute__((ext_vector_type(8))) short bf16x8;
typedef __attribute__((ext_vector_type(4))) float f32x4;
typedef __attribute__((ext_vector_type(8))) unsigned short us8;
typedef __attribute__((ext_vector_type(4))) unsigned short us4;

__device__ __forceinline__ unsigned short f2bf(float f) {
    unsigned int u = __float_as_uint(f);
    u += 0x7fffu + ((u >> 16) & 1u);   // RNE
    return (unsigned short)(u >> 16);
}
__device__ __forceinline__ float bf2f(unsigned short u) {
    return __uint_as_float(((unsigned int)u) << 16);
}

__device__ __forceinline__ void gl2lds16(const void* gsrc, void* ldsdst) {
    __builtin_amdgcn_global_load_lds(
        (const __attribute__((address_space(1))) unsigned int*)gsrc,
        (__attribute__((address_space(3))) unsigned int*)ldsdst, 16, 0, 0);
}

// ---------------- K1: fused LayerNorm (blocks 0..4095) + W_enc cvt (blocks 4096..20479) ----------------
__global__ __launch_bounds__(256) void prep_kernel(const float* __restrict__ x,
                                                   const float* __restrict__ gamma,
                                                   const float* __restrict__ beta,
                                                   unsigned short* __restrict__ nb,
                                                   const float* __restrict__ W,
                                                   unsigned short* __restrict__ Wb) {
    const int tid = threadIdx.x;
    if (blockIdx.x >= NTOK) {
        const size_t base = (size_t)(blockIdx.x - NTOK) * 1024;
        #pragma unroll
        for (int j = 0; j < 4; j++) {
            size_t i = base + j * 256 + tid;
            float4 f = ((const float4*)W)[i];
            us4 o;
            o.x = f2bf(f.x); o.y = f2bf(f.y); o.z = f2bf(f.z); o.w = f2bf(f.w);
            ((us4*)Wb)[i] = o;
        }
        return;
    }
    const int t = blockIdx.x;
    const float4 v = ((const float4*)(x + (size_t)t * D_))[tid];

    float s = v.x + v.y + v.z + v.w;
    #pragma unroll
    for (int off = 32; off > 0; off >>= 1) s += __shfl_down(s, off, 64);
    __shared__ float red[4];
    int wid = tid >> 6, lane = tid & 63;
    if (lane == 0) red[wid] = s;
    __syncthreads();
    float mu = (red[0] + red[1] + red[2] + red[3]) * (1.0f / D_);
    __syncthreads();

    float dx = v.x - mu, dy = v.y - mu, dz = v.z - mu, dw = v.w - mu;
    float ss = dx * dx + dy * dy + dz * dz + dw * dw;
    #pragma unroll
    for (int off = 32; off > 0; off >>= 1) ss += __shfl_down(ss, off, 64);
    if (lane == 0) red[wid] = ss;
    __syncthreads();
    float var = (red[0] + red[1] + red[2] + red[3]) * (1.0f / D_);
    float rs = rsqrtf(var + LN_EPS);

    const float4 g = ((const float4*)gamma)[tid];
    const float4 b = ((const float4*)beta)[tid];
    us4 o;
    o.x = f2bf(dx * rs * g.x + b.x);
    o.y = f2bf(dy * rs * g.y + b.y);
    o.z = f2bf(dz * rs * g.z + b.z);
    o.w = f2bf(dw * rs * g.w + b.w);
    ((us4*)(nb + (size_t)t * D_))[tid] = o;
}

// ---------------- K2: 256x256 bf16 MFMA GEMM + blockmax + streamed zero-fill ----------------
// R13 K-loop, plus: (a) bijective XCD swizzle (each XCD owns 8 dict-col panels,
// B L2-resident per XCD); (b) last iteration skips the wasteful wrap-around
// re-stage of tile 0 (uniform branch; vmcnt(0) on the final tile).
__global__ __launch_bounds__(512, 1) void gemm_kernel(const unsigned short* __restrict__ A,
                                                      const unsigned short* __restrict__ B,
                                                      unsigned short* __restrict__ L,
                                                      float* __restrict__ cbm,
                                                      float* __restrict__ Z) {
    __shared__ unsigned short lds[2][2][256][64];
    const int tid = threadIdx.x;
    const int lane = tid & 63;
    const int w = tid >> 6;
    const int wm = w >> 2, wn = w & 3;

    // XCD swizzle: lin%8 = XCD; XCD x covers col-blocks [8x,8x+8) over all 16 row-blocks.
    const int lin = blockIdx.x;
    const int cb_ = (lin & 7) * 8 + ((lin >> 3) >> 4);   // dict col-block 0..63
    const int rb_ = (lin >> 3) & 15;                     // token row-block 0..15
    const int col0 = cb_ * 256;
    const int row0 = rb_ * 256;

    f32x4 acc[8][4] = {};

    auto stage = [&](int b, int mat, const unsigned short* __restrict__ G,
                     int rbase, int k0, int h) {
        unsigned short* plane = &lds[b][mat][0][0];
        #pragma unroll
        for (int i = 0; i < 2; i++) {
            const int cb = h * 1024 + i * 512 + w * 64;   // wave-uniform chunk base
            const int c = cb + lane;
            const int r = c >> 3, sl = c & 7, g = sl ^ (r & 7);
            gl2lds16(G + (size_t)(rbase + r) * 1024 + k0 + g * 8, plane + (size_t)cb * 8);
        }
    };

    // prologue: stage tile 0 into buf 0
    stage(0, 0, A, row0, 0, 0);
    stage(0, 0, A, row0, 0, 1);
    stage(0, 1, B, col0, 0, 0);
    stage(0, 1, B, col0, 0, 1);

    const int arow = wm * 128 + (lane & 15);
    const int brow = wn * 64 + (lane & 15);
    const int kg = lane >> 4;

    for (int t = 0; t < 16; t++) {
        const int cur = t & 1, nxt = cur ^ 1;
        const int kn = (t + 1) * 64;

        // ---- phase 0: issue next A halves (except last iter); wait; kk0, n={0,1}
        if (t < 15) {
            stage(nxt, 0, A, row0, kn, 0);
            stage(nxt, 0, A, row0, kn, 1);
            asm volatile("s_waitcnt vmcnt(4)" ::: "memory");
        } else {
            asm volatile("s_waitcnt vmcnt(0)" ::: "memory");
        }
        __builtin_amdgcn_s_barrier();
        __builtin_amdgcn_sched_barrier(0);
        asm volatile("" ::: "memory");

        bf16x8 af[8];
        #pragma unroll
        for (int m = 0; m < 8; m++) {
            const int r = arow + m * 16;
            af[m] = *(const bf16x8*)&lds[cur][0][r][(kg ^ (r & 7)) * 8];
        }
        bf16x8 b0, b1;
        { const int r = brow;      b0 = *(const bf16x8*)&lds[cur][1][r][(kg ^ (r & 7)) * 8]; }
        { const int r = brow + 16; b1 = *(const bf16x8*)&lds[cur][1][r][(kg ^ (r & 7)) * 8]; }
        __builtin_amdgcn_s_setprio(1);
        #pragma unroll
        for (int m = 0; m < 8; m++) {
            acc[m][0] = __builtin_amdgcn_mfma_f32_16x16x32_bf16(af[m], b0, acc[m][0], 0, 0, 0);
            acc[m][1] = __builtin_amdgcn_mfma_f32_16x16x32_bf16(af[m], b1, acc[m][1], 0, 0, 0);
        }
        __builtin_amdgcn_s_setprio(0);

        // ---- phase 1: issue next B halves (except last iter); kk0, n={2,3}
        if (t < 15) {
            stage(nxt, 1, B, col0, kn, 0);
            stage(nxt, 1, B, col0, kn, 1);
        }
        { const int r = brow + 32; b0 = *(const bf16x8*)&lds[cur][1][r][(kg ^ (r & 7)) * 8]; }
        { const int r = brow + 48; b1 = *(const bf16x8*)&lds[cur][1][r][(kg ^ (r & 7)) * 8]; }
        __builtin_amdgcn_s_setprio(1);
        #pragma unroll
        for (int m = 0; m < 8; m++) {
            acc[m][2] = __builtin_amdgcn_mfma_f32_16x16x32_bf16(af[m], b0, acc[m][2], 0, 0, 0);
            acc[m][3] = __builtin_amdgcn_mfma_f32_16x16x32_bf16(af[m], b1, acc[m][3], 0, 0, 0);
        }
        __builtin_amdgcn_s_setprio(0);

        // ---- phase 2: kk1, n={0,1}
        #pragma unroll
        for (int m = 0; m < 8; m++) {
            const int r = arow + m * 16;
            af[m] = *(const bf16x8*)&lds[cur][0][r][((4 + kg) ^ (r & 7)) * 8];
        }
        { const int r = brow;      b0 = *(const bf16x8*)&lds[cur][1][r][((4 + kg) ^ (r & 7)) * 8]; }
        { const int r = brow + 16; b1 = *(const bf16x8*)&lds[cur][1][r][((4 + kg) ^ (r & 7)) * 8]; }
        __builtin_amdgcn_s_setprio(1);
        #pragma unroll
        for (int m = 0; m < 8; m++) {
            acc[m][0] = __builtin_amdgcn_mfma_f32_16x16x32_bf16(af[m], b0, acc[m][0], 0, 0, 0);
            acc[m][1] = __builtin_amdgcn_mfma_f32_16x16x32_bf16(af[m], b1, acc[m][1], 0, 0, 0);
        }
        __builtin_amdgcn_s_setprio(0);

        // ---- phase 3: kk1, n={2,3}
        { const int r = brow + 32; b0 = *(const bf16x8*)&lds[cur][1][r][((4 + kg) ^ (r & 7)) * 8]; }
        { const int r = brow + 48; b1 = *(const bf16x8*)&lds[cur][1][r][((4 + kg) ^ (r & 7)) * 8]; }
        __builtin_amdgcn_s_setprio(1);
        #pragma unroll
        for (int m = 0; m < 8; m++) {
            acc[m][2] = __builtin_amdgcn_mfma_f32_16x16x32_bf16(af[m], b0, acc[m][2], 0, 0, 0);
            acc[m][3] = __builtin_amdgcn_mfma_f32_16x16x32_bf16(af[m], b1, acc[m][3], 0, 0, 0);
        }
        __builtin_amdgcn_s_setprio(0);

        __builtin_amdgcn_s_barrier();
        __builtin_amdgcn_sched_barrier(0);
        asm volatile("" ::: "memory");
    }

    // ---- blockmax: per-(m,r) row max over this thread's 16 cols, fully static ----
    float rmax[8][4];
    #pragma unroll
    for (int m = 0; m < 8; m++)
        #pragma unroll
        for (int r = 0; r < 4; r++)
            rmax[m][r] = fmaxf(fmaxf(acc[m][0][r], acc[m][1][r]),
                               fmaxf(acc[m][2][r], acc[m][3][r]));
    #pragma unroll
    for (int m = 0; m < 8; m++)
        #pragma unroll
        for (int r = 0; r < 4; r++) {
            float v = rmax[m][r];
            v = fmaxf(v, __shfl_xor(v, 1, 64));
            v = fmaxf(v, __shfl_xor(v, 2, 64));
            v = fmaxf(v, __shfl_xor(v, 4, 64));
            v = fmaxf(v, __shfl_xor(v, 8, 64));
            rmax[m][r] = v;
        }

    // no staging DMA in flight (last iter skipped it); barrier before LDS reuse
    asm volatile("s_waitcnt vmcnt(0)" ::: "memory");
    __builtin_amdgcn_s_barrier();
    __builtin_amdgcn_sched_barrier(0);

    float* bm = (float*)&lds[0][0][0][0];   // [4 wn][256 rows] = 4 KB
    if ((lane & 15) == 0) {
        const int q = lane >> 4;
        #pragma unroll
        for (int m = 0; m < 8; m++)
            #pragma unroll
            for (int r = 0; r < 4; r++)
                bm[wn * 256 + wm * 128 + m * 16 + q * 4 + r] = rmax[m][r];
    }
    __syncthreads();
    if (tid < 256) {
        const float b0 = fmaxf(fmaxf(bm[tid], bm[256 + tid]),
                               fmaxf(bm[512 + tid], bm[768 + tid]));
        cbm[(size_t)(row0 + tid) * 64 + cb_] = b0;
    }

    // logits write: C/D layout col=lane&15, row=(lane>>4)*4+reg
    #pragma unroll
    for (int m = 0; m < 8; m++) {
        const int rb = row0 + wm * 128 + m * 16 + (lane >> 4) * 4;
        #pragma unroll
        for (int n = 0; n < 4; n++) {
            const int col = col0 + wn * 64 + n * 16 + (lane & 15);
            #pragma unroll
            for (int r = 0; r < 4; r++)
                L[(size_t)(rb + r) * DICT_ + col] = f2bf(acc[m][n][r]);
        }
    }

    // ---- streamed zero-fill of this block's 256 KB slice of the sparse output ----
    {
        const f32x4 z = {0.f, 0.f, 0.f, 0.f};
        f32x4* zrow = (f32x4*)(Z + (size_t)lin * 65536);
        #pragma unroll
        for (int i = 0; i < 32; i++)
            __builtin_nontemporal_store(z, zrow + i * 512 + tid);
    }
}

// ---------------- K3: fused select: blocks -> candidates -> exact refine -> patch + recon ----------------
__global__ __launch_bounds__(256) void select_kernel(const float* __restrict__ cbm,
                                                     const unsigned short* __restrict__ L,
                                                     const float* __restrict__ x,
                                                     const float* __restrict__ gamma,
                                                     const float* __restrict__ beta,
                                                     const float* __restrict__ Wenc,
                                                     const float* __restrict__ Wdict,
                                                     float* __restrict__ sparse,
                                                     float* __restrict__ recon) {
    const int token = blockIdx.x;
    const int tid = threadIdx.x;
    const int lane = tid & 63;
    const int wv4 = tid >> 6;

    __shared__ float red[4];
    __shared__ float ln[D_];
    __shared__ int blksel[NBLKSEL];

    // ---- LayerNorm (fp32, matches reference) ----
    const float4 v = ((const float4*)(x + (size_t)token * D_))[tid];
    float s = v.x + v.y + v.z + v.w;
    #pragma unroll
    for (int off = 32; off > 0; off >>= 1) s += __shfl_down(s, off, 64);
    if (lane == 0) red[wv4] = s;
    __syncthreads();
    float mu = (red[0] + red[1] + red[2] + red[3]) * (1.0f / D_);
    __syncthreads();
    float dx = v.x - mu, dy = v.y - mu, dz = v.z - mu, dw = v.w - mu;
    float ss = dx * dx + dy * dy + dz * dz + dw * dw;
    #pragma unroll
    for (int off = 32; off > 0; off >>= 1) ss += __shfl_down(ss, off, 64);
    if (lane == 0) red[wv4] = ss;
    __syncthreads();
    float var = (red[0] + red[1] + red[2] + red[3]) * (1.0f / D_);
    float rs = rsqrtf(var + LN_EPS);
    const float4 g = ((const float4*)gamma)[tid];
    const float4 b = ((const float4*)beta)[tid];
    float4 o;
    o.x = dx * rs * g.x + b.x;
    o.y = dy * rs * g.y + b.y;
    o.z = dz * rs * g.z + b.z;
    o.w = dw * rs * g.w + b.w;
    ((float4*)ln)[tid] = o;

    // ---- top-12 blocks by blockmax (deterministic: k-th value lies in top-k blocks) ----
    if (tid < 64) {
        float bv0 = cbm[(size_t)token * 64 + tid];
        for (int round = 0; round < NBLKSEL; round++) {
            float bv = bv0; int bi = tid;
            #pragma unroll
            for (int off = 32; off > 0; off >>= 1) {
                const float ov = __shfl_xor(bv, off, 64);
                const int oi = __shfl_xor(bi, off, 64);
                if (ov > bv || (ov == bv && oi < bi)) { bv = ov; bi = oi; }
            }
            if (tid == 0) blksel[round] = bi;
            if (tid == bi) bv0 = -FLT_MAX;
        }
    }
    __syncthreads();

    // ---- scan 12 selected blocks (3072 cols) -> per-thread top-4 ----
    float v4[4]; int id4[4];
    #pragma unroll
    for (int j = 0; j < 4; j++) { v4[j] = -FLT_MAX; id4[j] = -1; }
    #pragma unroll
    for (int pass = 0; pass < 2; pass++) {
        if (pass == 1 && tid >= 128) break;
        const int b = blksel[pass * 8 + (tid >> 5)];
        const int colbase = b * 256 + (tid & 31) * 8;
        const us8 u = *(const us8*)&L[(size_t)token * DICT_ + colbase];
        #pragma unroll
        for (int e = 0; e < 8; e++) {
            const float f = bf2f(u[e]);
            if (f > v4[3]) {
                v4[3] = f; id4[3] = colbase + e;
                #pragma unroll
                for (int q = 3; q > 0; q--) {
                    if (v4[q] > v4[q - 1]) {
                        float tf = v4[q]; v4[q] = v4[q - 1]; v4[q - 1] = tf;
                        int ti = id4[q]; id4[q] = id4[q - 1]; id4[q - 1] = ti;
                    }
                }
            }
        }
    }

    __shared__ float hv[256];
    __shared__ int hi[256];
    __shared__ int cnd[NCAND];
    __shared__ int wt;
    hv[tid] = v4[0];
    hi[tid] = id4[0];
    int myp = 0;

    for (int round = 0; round < NCAND; round++) {
        __syncthreads();
        if (tid < 64) {
            float bv = hv[tid]; int bt = tid;
            #pragma unroll
            for (int q = 1; q < 4; q++) {
                const int t2 = tid + q * 64;
                const float v2 = hv[t2];
                if (v2 > bv || (v2 == bv && t2 < bt)) { bv = v2; bt = t2; }
            }
            #pragma unroll
            for (int off = 32; off > 0; off >>= 1) {
                const float ov = __shfl_down(bv, off, 64);
                const int ot = __shfl_down(bt, off, 64);
                if (ov > bv || (ov == bv && ot < bt)) { bv = ov; bt = ot; }
            }
            if (tid == 0) wt = bt;
        }
        __syncthreads();
        if (tid == wt) {
            cnd[round] = hi[tid];
            myp++;
            if (myp < 4) { hv[tid] = v4[myp]; hi[tid] = id4[myp]; }
            else { hv[tid] = -FLT_MAX; hi[tid] = -1; }
        }
    }
    __syncthreads();

    // ---- exact fp32 refine of the 12 candidates ----
    __shared__ float dv[NCAND];
    __shared__ int di_s[NCAND];
    for (int c = wv4; c < NCAND; c += 4) {
        const int di = cnd[c];
        const float4* wr = (const float4*)(Wenc + (size_t)di * D_);
        float acc = 0.f;
        #pragma unroll
        for (int j = 0; j < 4; j++) {
            const float4 q = wr[j * 64 + lane];
            const float4 p = ((const float4*)ln)[j * 64 + lane];
            acc += q.x * p.x + q.y * p.y + q.z * p.z + q.w * p.w;
        }
        #pragma unroll
        for (int off = 32; off > 0; off >>= 1) acc += __shfl_down(acc, off, 64);
        if (lane == 0) { dv[c] = acc; di_s[c] = di; }
    }
    __syncthreads();

    __shared__ float wvv[TOPK];
    __shared__ int wii[TOPK];
    if (tid == 0) {
        unsigned int used = 0;
        for (int p = 0; p < TOPK; p++) {
            float bv = -FLT_MAX; int bc = -1;
            for (int c = 0; c < NCAND; c++) {
                if (used & (1u << c)) continue;
                const float cv = dv[c];
                if (cv > bv || (cv == bv && di_s[c] < ((bc >= 0) ? di_s[bc] : 0x7fffffff))) { bv = cv; bc = c; }
            }
            used |= 1u << bc;
            wvv[p] = dv[bc]; wii[p] = di_s[bc];
        }
    }
    __syncthreads();

    // ---- patch the 8 values (zeros already streamed by gemm) + reconstruction ----
    float4 wr8[TOPK];
    #pragma unroll
    for (int j = 0; j < TOPK; j++)
        wr8[j] = ((const float4*)(Wdict + (size_t)wii[j] * D_))[tid];

    if (tid < TOPK)
        sparse[(size_t)token * DICT_ + wii[tid]] = wvv[tid];

    float4 acc = {0.f, 0.f, 0.f, 0.f};
    #pragma unroll
    for (int j = 0; j < TOPK; j++) {
        const float c = wvv[j];
        acc.x = fmaf(c, wr8[j].x, acc.x);
        acc.y = fmaf(c, wr8[j].y, acc.y);
        acc.z = fmaf(c, wr8[j].z, acc.z);
        acc.w = fmaf(c, wr8[j].w, acc.w);
    }
    ((float4*)(recon + (size_t)token * D_))[tid] = acc;
}

extern "C" void kernel_launch(void* const* d_in, const int* in_sizes, int n_in,
                              void* d_out, int out_size, void* d_ws, size_t ws_size,
                              hipStream_t stream) {
    const float* x = (const float*)d_in[0];
    const float* gamma = (const float*)d_in[1];
    const float* beta = (const float*)d_in[2];
    const float* Wenc = (const float*)d_in[3];
    const float* Wdict = (const float*)d_in[4];

    float* recon = (float*)d_out;
    float* sparse = (float*)d_out + (size_t)NTOK * D_;

    // scratch in d_ws (~178 MB)
    unsigned short* Lg = (unsigned short*)d_ws;                   // bf16 logits, 134 MB
    unsigned short* We = Lg + (size_t)NTOK * DICT_;               // bf16 W_enc, 33.5 MB
    unsigned short* Nb = We + (size_t)DICT_ * D_;                 // bf16 normed, 8 MB
    float* cbm = (float*)(Nb + (size_t)NTOK * D_);                // 4096*64 f32, 1 MB

    prep_kernel<<<NTOK + DICT_ * D_ / 4096, 256, 0, stream>>>(x, gamma, beta, Nb, Wenc, We);

    gemm_kernel<<<1024, 512, 0, stream>>>(Nb, We, Lg, cbm, sparse);

    select_kernel<<<NTOK, 256, 0, stream>>>(cbm, Lg, x, gamma, beta, Wenc, Wdict,
                                            sparse, recon);
}

// Round 16
// 278.431 us; speedup vs baseline: 1.0893x; 1.0893x over previous
//
#include <hip/hip_runtime.h>
#include <hip/hip_bf16.h>
#include <cfloat>

#define NTOK 4096
#define D_ 1024
#define DICT_ 16384
#define TOPK 8
#define NCAND 12
#define NBLKSEL 12
#define LN_EPS 1e-5f

typedef __attribute__((ext_vector_type(8))) short bf16x8;
typedef __attribute__((ext_vector_type(4))) float f32x4;
typedef __attribute__((ext_vector_type(8))) unsigned short us8;
typedef __attribute__((ext_vector_type(4))) unsigned short us4;

__device__ __forceinline__ unsigned short f2bf(float f) {
    unsigned int u = __float_as_uint(f);
    u += 0x7fffu + ((u >> 16) & 1u);   // RNE
    return (unsigned short)(u >> 16);
}
__device__ __forceinline__ float bf2f(unsigned short u) {
    return __uint_as_float(((unsigned int)u) << 16);
}

__device__ __forceinline__ void gl2lds16(const void* gsrc, void* ldsdst) {
    __builtin_amdgcn_global_load_lds(
        (const __attribute__((address_space(1))) unsigned int*)gsrc,
        (__attribute__((address_space(3))) unsigned int*)ldsdst, 16, 0, 0);
}

// ---------------- K1: fused LayerNorm (blocks 0..4095) + W_enc cvt (blocks 4096..20479) ----------------
__global__ __launch_bounds__(256) void prep_kernel(const float* __restrict__ x,
                                                   const float* __restrict__ gamma,
                                                   const float* __restrict__ beta,
                                                   unsigned short* __restrict__ nb,
                                                   const float* __restrict__ W,
                                                   unsigned short* __restrict__ Wb) {
    const int tid = threadIdx.x;
    if (blockIdx.x >= NTOK) {
        const size_t base = (size_t)(blockIdx.x - NTOK) * 1024;
        #pragma unroll
        for (int j = 0; j < 4; j++) {
            size_t i = base + j * 256 + tid;
            float4 f = ((const float4*)W)[i];
            us4 o;
            o.x = f2bf(f.x); o.y = f2bf(f.y); o.z = f2bf(f.z); o.w = f2bf(f.w);
            ((us4*)Wb)[i] = o;
        }
        return;
    }
    const int t = blockIdx.x;
    const float4 v = ((const float4*)(x + (size_t)t * D_))[tid];

    float s = v.x + v.y + v.z + v.w;
    #pragma unroll
    for (int off = 32; off > 0; off >>= 1) s += __shfl_down(s, off, 64);
    __shared__ float red[4];
    int wid = tid >> 6, lane = tid & 63;
    if (lane == 0) red[wid] = s;
    __syncthreads();
    float mu = (red[0] + red[1] + red[2] + red[3]) * (1.0f / D_);
    __syncthreads();

    float dx = v.x - mu, dy = v.y - mu, dz = v.z - mu, dw = v.w - mu;
    float ss = dx * dx + dy * dy + dz * dz + dw * dw;
    #pragma unroll
    for (int off = 32; off > 0; off >>= 1) ss += __shfl_down(ss, off, 64);
    if (lane == 0) red[wid] = ss;
    __syncthreads();
    float var = (red[0] + red[1] + red[2] + red[3]) * (1.0f / D_);
    float rs = rsqrtf(var + LN_EPS);

    const float4 g = ((const float4*)gamma)[tid];
    const float4 b = ((const float4*)beta)[tid];
    us4 o;
    o.x = f2bf(dx * rs * g.x + b.x);
    o.y = f2bf(dy * rs * g.y + b.y);
    o.z = f2bf(dz * rs * g.z + b.z);
    o.w = f2bf(dw * rs * g.w + b.w);
    ((us4*)(nb + (size_t)t * D_))[tid] = o;
}

// ---------------- K2: 256x256 bf16 MFMA GEMM + blockmax + streamed zero-fill ----------------
// R13/R14 version exactly: uniform wrap-around K-loop (uniformity is load-bearing:
// R15's last-iter branch cost -12% MfmaUtil), linear dim3(64,16) grid (default
// dispatch order already gives per-XCD A-panel sharing; R15's swizzle regressed).
__global__ __launch_bounds__(512, 1) void gemm_kernel(const unsigned short* __restrict__ A,
                                                      const unsigned short* __restrict__ B,
                                                      unsigned short* __restrict__ L,
                                                      float* __restrict__ cbm,
                                                      float* __restrict__ Z) {
    __shared__ unsigned short lds[2][2][256][64];
    const int tid = threadIdx.x;
    const int lane = tid & 63;
    const int w = tid >> 6;
    const int wm = w >> 2, wn = w & 3;
    const int col0 = blockIdx.x * 256;   // dict cols
    const int row0 = blockIdx.y * 256;   // token rows

    f32x4 acc[8][4] = {};

    auto stage = [&](int b, int mat, const unsigned short* __restrict__ G,
                     int rbase, int k0, int h) {
        unsigned short* plane = &lds[b][mat][0][0];
        #pragma unroll
        for (int i = 0; i < 2; i++) {
            const int cb = h * 1024 + i * 512 + w * 64;   // wave-uniform chunk base
            const int c = cb + lane;
            const int r = c >> 3, sl = c & 7, g = sl ^ (r & 7);
            gl2lds16(G + (size_t)(rbase + r) * 1024 + k0 + g * 8, plane + (size_t)cb * 8);
        }
    };

    // prologue: stage tile 0 into buf 0
    stage(0, 0, A, row0, 0, 0);
    stage(0, 0, A, row0, 0, 1);
    stage(0, 1, B, col0, 0, 0);
    stage(0, 1, B, col0, 0, 1);

    const int arow = wm * 128 + (lane & 15);
    const int brow = wn * 64 + (lane & 15);
    const int kg = lane >> 4;

    for (int t = 0; t < 16; t++) {
        const int cur = t & 1, nxt = cur ^ 1;
        const int kn = ((t + 1) & 15) * 64;   // wrap-around keeps loop uniform

        // ---- phase 0: issue next A halves; wait tile t (leave 4 in flight); kk0, n={0,1}
        stage(nxt, 0, A, row0, kn, 0);
        stage(nxt, 0, A, row0, kn, 1);
        asm volatile("s_waitcnt vmcnt(4)" ::: "memory");
        __builtin_amdgcn_s_barrier();
        __builtin_amdgcn_sched_barrier(0);
        asm volatile("" ::: "memory");

        bf16x8 af[8];
        #pragma unroll
        for (int m = 0; m < 8; m++) {
            const int r = arow + m * 16;
            af[m] = *(const bf16x8*)&lds[cur][0][r][(kg ^ (r & 7)) * 8];
        }
        bf16x8 b0, b1;
        { const int r = brow;      b0 = *(const bf16x8*)&lds[cur][1][r][(kg ^ (r & 7)) * 8]; }
        { const int r = brow + 16; b1 = *(const bf16x8*)&lds[cur][1][r][(kg ^ (r & 7)) * 8]; }
        __builtin_amdgcn_s_setprio(1);
        #pragma unroll
        for (int m = 0; m < 8; m++) {
            acc[m][0] = __builtin_amdgcn_mfma_f32_16x16x32_bf16(af[m], b0, acc[m][0], 0, 0, 0);
            acc[m][1] = __builtin_amdgcn_mfma_f32_16x16x32_bf16(af[m], b1, acc[m][1], 0, 0, 0);
        }
        __builtin_amdgcn_s_setprio(0);

        // ---- phase 1: issue next B halves; kk0, n={2,3}
        stage(nxt, 1, B, col0, kn, 0);
        stage(nxt, 1, B, col0, kn, 1);
        { const int r = brow + 32; b0 = *(const bf16x8*)&lds[cur][1][r][(kg ^ (r & 7)) * 8]; }
        { const int r = brow + 48; b1 = *(const bf16x8*)&lds[cur][1][r][(kg ^ (r & 7)) * 8]; }
        __builtin_amdgcn_s_setprio(1);
        #pragma unroll
        for (int m = 0; m < 8; m++) {
            acc[m][2] = __builtin_amdgcn_mfma_f32_16x16x32_bf16(af[m], b0, acc[m][2], 0, 0, 0);
            acc[m][3] = __builtin_amdgcn_mfma_f32_16x16x32_bf16(af[m], b1, acc[m][3], 0, 0, 0);
        }
        __builtin_amdgcn_s_setprio(0);

        // ---- phase 2: kk1, n={0,1}
        #pragma unroll
        for (int m = 0; m < 8; m++) {
            const int r = arow + m * 16;
            af[m] = *(const bf16x8*)&lds[cur][0][r][((4 + kg) ^ (r & 7)) * 8];
        }
        { const int r = brow;      b0 = *(const bf16x8*)&lds[cur][1][r][((4 + kg) ^ (r & 7)) * 8]; }
        { const int r = brow + 16; b1 = *(const bf16x8*)&lds[cur][1][r][((4 + kg) ^ (r & 7)) * 8]; }
        __builtin_amdgcn_s_setprio(1);
        #pragma unroll
        for (int m = 0; m < 8; m++) {
            acc[m][0] = __builtin_amdgcn_mfma_f32_16x16x32_bf16(af[m], b0, acc[m][0], 0, 0, 0);
            acc[m][1] = __builtin_amdgcn_mfma_f32_16x16x32_bf16(af[m], b1, acc[m][1], 0, 0, 0);
        }
        __builtin_amdgcn_s_setprio(0);

        // ---- phase 3: kk1, n={2,3}
        { const int r = brow + 32; b0 = *(const bf16x8*)&lds[cur][1][r][((4 + kg) ^ (r & 7)) * 8]; }
        { const int r = brow + 48; b1 = *(const bf16x8*)&lds[cur][1][r][((4 + kg) ^ (r & 7)) * 8]; }
        __builtin_amdgcn_s_setprio(1);
        #pragma unroll
        for (int m = 0; m < 8; m++) {
            acc[m][2] = __builtin_amdgcn_mfma_f32_16x16x32_bf16(af[m], b0, acc[m][2], 0, 0, 0);
            acc[m][3] = __builtin_amdgcn_mfma_f32_16x16x32_bf16(af[m], b1, acc[m][3], 0, 0, 0);
        }
        __builtin_amdgcn_s_setprio(0);

        __builtin_amdgcn_s_barrier();
        __builtin_amdgcn_sched_barrier(0);
        asm volatile("" ::: "memory");
    }

    // ---- blockmax: per-(m,r) row max over this thread's 16 cols, fully static ----
    float rmax[8][4];
    #pragma unroll
    for (int m = 0; m < 8; m++)
        #pragma unroll
        for (int r = 0; r < 4; r++)
            rmax[m][r] = fmaxf(fmaxf(acc[m][0][r], acc[m][1][r]),
                               fmaxf(acc[m][2][r], acc[m][3][r]));
    #pragma unroll
    for (int m = 0; m < 8; m++)
        #pragma unroll
        for (int r = 0; r < 4; r++) {
            float v = rmax[m][r];
            v = fmaxf(v, __shfl_xor(v, 1, 64));
            v = fmaxf(v, __shfl_xor(v, 2, 64));
            v = fmaxf(v, __shfl_xor(v, 4, 64));
            v = fmaxf(v, __shfl_xor(v, 8, 64));
            rmax[m][r] = v;
        }

    // drain in-flight wrap-around staging DMA, then reuse LDS for cross-wave max
    asm volatile("s_waitcnt vmcnt(0)" ::: "memory");
    __builtin_amdgcn_s_barrier();
    __builtin_amdgcn_sched_barrier(0);

    float* bm = (float*)&lds[0][0][0][0];   // [4 wn][256 rows] = 4 KB
    if ((lane & 15) == 0) {
        const int q = lane >> 4;
        #pragma unroll
        for (int m = 0; m < 8; m++)
            #pragma unroll
            for (int r = 0; r < 4; r++)
                bm[wn * 256 + wm * 128 + m * 16 + q * 4 + r] = rmax[m][r];
    }
    __syncthreads();
    if (tid < 256) {
        const float b0 = fmaxf(fmaxf(bm[tid], bm[256 + tid]),
                               fmaxf(bm[512 + tid], bm[768 + tid]));
        cbm[(size_t)(row0 + tid) * 64 + blockIdx.x] = b0;
    }

    // logits write: C/D layout col=lane&15, row=(lane>>4)*4+reg
    #pragma unroll
    for (int m = 0; m < 8; m++) {
        const int rb = row0 + wm * 128 + m * 16 + (lane >> 4) * 4;
        #pragma unroll
        for (int n = 0; n < 4; n++) {
            const int col = col0 + wn * 64 + n * 16 + (lane & 15);
            #pragma unroll
            for (int r = 0; r < 4; r++)
                L[(size_t)(rb + r) * DICT_ + col] = f2bf(acc[m][n][r]);
        }
    }

    // ---- streamed zero-fill of this block's 256 KB slice of the sparse output ----
    {
        const f32x4 z = {0.f, 0.f, 0.f, 0.f};
        f32x4* zrow = (f32x4*)(Z + (size_t)(blockIdx.y * 64 + blockIdx.x) * 65536);
        #pragma unroll
        for (int i = 0; i < 32; i++)
            __builtin_nontemporal_store(z, zrow + i * 512 + tid);
    }
}

// ---------------- K3: fused select: blocks -> candidates -> exact refine -> patch + recon ----------------
__global__ __launch_bounds__(256) void select_kernel(const float* __restrict__ cbm,
                                                     const unsigned short* __restrict__ L,
                                                     const float* __restrict__ x,
                                                     const float* __restrict__ gamma,
                                                     const float* __restrict__ beta,
                                                     const float* __restrict__ Wenc,
                                                     const float* __restrict__ Wdict,
                                                     float* __restrict__ sparse,
                                                     float* __restrict__ recon) {
    const int token = blockIdx.x;
    const int tid = threadIdx.x;
    const int lane = tid & 63;
    const int wv4 = tid >> 6;

    __shared__ float red[4];
    __shared__ float ln[D_];
    __shared__ int blksel[NBLKSEL];

    // ---- LayerNorm (fp32, matches reference) ----
    const float4 v = ((const float4*)(x + (size_t)token * D_))[tid];
    float s = v.x + v.y + v.z + v.w;
    #pragma unroll
    for (int off = 32; off > 0; off >>= 1) s += __shfl_down(s, off, 64);
    if (lane == 0) red[wv4] = s;
    __syncthreads();
    float mu = (red[0] + red[1] + red[2] + red[3]) * (1.0f / D_);
    __syncthreads();
    float dx = v.x - mu, dy = v.y - mu, dz = v.z - mu, dw = v.w - mu;
    float ss = dx * dx + dy * dy + dz * dz + dw * dw;
    #pragma unroll
    for (int off = 32; off > 0; off >>= 1) ss += __shfl_down(ss, off, 64);
    if (lane == 0) red[wv4] = ss;
    __syncthreads();
    float var = (red[0] + red[1] + red[2] + red[3]) * (1.0f / D_);
    float rs = rsqrtf(var + LN_EPS);
    const float4 g = ((const float4*)gamma)[tid];
    const float4 b = ((const float4*)beta)[tid];
    float4 o;
    o.x = dx * rs * g.x + b.x;
    o.y = dy * rs * g.y + b.y;
    o.z = dz * rs * g.z + b.z;
    o.w = dw * rs * g.w + b.w;
    ((float4*)ln)[tid] = o;

    // ---- top-12 blocks by blockmax (deterministic: k-th value lies in top-k blocks) ----
    if (tid < 64) {
        float bv0 = cbm[(size_t)token * 64 + tid];
        for (int round = 0; round < NBLKSEL; round++) {
            float bv = bv0; int bi = tid;
            #pragma unroll
            for (int off = 32; off > 0; off >>= 1) {
                const float ov = __shfl_xor(bv, off, 64);
                const int oi = __shfl_xor(bi, off, 64);
                if (ov > bv || (ov == bv && oi < bi)) { bv = ov; bi = oi; }
            }
            if (tid == 0) blksel[round] = bi;
            if (tid == bi) bv0 = -FLT_MAX;
        }
    }
    __syncthreads();

    // ---- scan 12 selected blocks (3072 cols) -> per-thread top-4 ----
    float v4[4]; int id4[4];
    #pragma unroll
    for (int j = 0; j < 4; j++) { v4[j] = -FLT_MAX; id4[j] = -1; }
    #pragma unroll
    for (int pass = 0; pass < 2; pass++) {
        if (pass == 1 && tid >= 128) break;
        const int b = blksel[pass * 8 + (tid >> 5)];
        const int colbase = b * 256 + (tid & 31) * 8;
        const us8 u = *(const us8*)&L[(size_t)token * DICT_ + colbase];
        #pragma unroll
        for (int e = 0; e < 8; e++) {
            const float f = bf2f(u[e]);
            if (f > v4[3]) {
                v4[3] = f; id4[3] = colbase + e;
                #pragma unroll
                for (int q = 3; q > 0; q--) {
                    if (v4[q] > v4[q - 1]) {
                        float tf = v4[q]; v4[q] = v4[q - 1]; v4[q - 1] = tf;
                        int ti = id4[q]; id4[q] = id4[q - 1]; id4[q - 1] = ti;
                    }
                }
            }
        }
    }

    __shared__ float hv[256];
    __shared__ int hi[256];
    __shared__ int cnd[NCAND];
    __shared__ int wt;
    hv[tid] = v4[0];
    hi[tid] = id4[0];
    int myp = 0;

    for (int round = 0; round < NCAND; round++) {
        __syncthreads();
        if (tid < 64) {
            float bv = hv[tid]; int bt = tid;
            #pragma unroll
            for (int q = 1; q < 4; q++) {
                const int t2 = tid + q * 64;
                const float v2 = hv[t2];
                if (v2 > bv || (v2 == bv && t2 < bt)) { bv = v2; bt = t2; }
            }
            #pragma unroll
            for (int off = 32; off > 0; off >>= 1) {
                const float ov = __shfl_down(bv, off, 64);
                const int ot = __shfl_down(bt, off, 64);
                if (ov > bv || (ov == bv && ot < bt)) { bv = ov; bt = ot; }
            }
            if (tid == 0) wt = bt;
        }
        __syncthreads();
        if (tid == wt) {
            cnd[round] = hi[tid];
            myp++;
            if (myp < 4) { hv[tid] = v4[myp]; hi[tid] = id4[myp]; }
            else { hv[tid] = -FLT_MAX; hi[tid] = -1; }
        }
    }
    __syncthreads();

    // ---- exact fp32 refine of the 12 candidates ----
    __shared__ float dv[NCAND];
    __shared__ int di_s[NCAND];
    for (int c = wv4; c < NCAND; c += 4) {
        const int di = cnd[c];
        const float4* wr = (const float4*)(Wenc + (size_t)di * D_);
        float acc = 0.f;
        #pragma unroll
        for (int j = 0; j < 4; j++) {
            const float4 q = wr[j * 64 + lane];
            const float4 p = ((const float4*)ln)[j * 64 + lane];
            acc += q.x * p.x + q.y * p.y + q.z * p.z + q.w * p.w;
        }
        #pragma unroll
        for (int off = 32; off > 0; off >>= 1) acc += __shfl_down(acc, off, 64);
        if (lane == 0) { dv[c] = acc; di_s[c] = di; }
    }
    __syncthreads();

    __shared__ float wvv[TOPK];
    __shared__ int wii[TOPK];
    if (tid == 0) {
        unsigned int used = 0;
        for (int p = 0; p < TOPK; p++) {
            float bv = -FLT_MAX; int bc = -1;
            for (int c = 0; c < NCAND; c++) {
                if (used & (1u << c)) continue;
                const float cv = dv[c];
                if (cv > bv || (cv == bv && di_s[c] < ((bc >= 0) ? di_s[bc] : 0x7fffffff))) { bv = cv; bc = c; }
            }
            used |= 1u << bc;
            wvv[p] = dv[bc]; wii[p] = di_s[bc];
        }
    }
    __syncthreads();

    // ---- patch the 8 values (zeros already streamed by gemm) + reconstruction ----
    float4 wr8[TOPK];
    #pragma unroll
    for (int j = 0; j < TOPK; j++)
        wr8[j] = ((const float4*)(Wdict + (size_t)wii[j] * D_))[tid];

    if (tid < TOPK)
        sparse[(size_t)token * DICT_ + wii[tid]] = wvv[tid];

    float4 acc = {0.f, 0.f, 0.f, 0.f};
    #pragma unroll
    for (int j = 0; j < TOPK; j++) {
        const float c = wvv[j];
        acc.x = fmaf(c, wr8[j].x, acc.x);
        acc.y = fmaf(c, wr8[j].y, acc.y);
        acc.z = fmaf(c, wr8[j].z, acc.z);
        acc.w = fmaf(c, wr8[j].w, acc.w);
    }
    ((float4*)(recon + (size_t)token * D_))[tid] = acc;
}

extern "C" void kernel_launch(void* const* d_in, const int* in_sizes, int n_in,
                              void* d_out, int out_size, void* d_ws, size_t ws_size,
                              hipStream_t stream) {
    const float* x = (const float*)d_in[0];
    const float* gamma = (const float*)d_in[1];
    const float* beta = (const float*)d_in[2];
    const float* Wenc = (const float*)d_in[3];
    const float* Wdict = (const float*)d_in[4];

    float* recon = (float*)d_out;
    float* sparse = (float*)d_out + (size_t)NTOK * D_;

    // scratch in d_ws (~178 MB)
    unsigned short* Lg = (unsigned short*)d_ws;                   // bf16 logits, 134 MB
    unsigned short* We = Lg + (size_t)NTOK * DICT_;               // bf16 W_enc, 33.5 MB
    unsigned short* Nb = We + (size_t)DICT_ * D_;                 // bf16 normed, 8 MB
    float* cbm = (float*)(Nb + (size_t)NTOK * D_);                // 4096*64 f32, 1 MB

    prep_kernel<<<NTOK + DICT_ * D_ / 4096, 256, 0, stream>>>(x, gamma, beta, Nb, Wenc, We);

    dim3 gg(DICT_ / 256, NTOK / 256);
    gemm_kernel<<<gg, 512, 0, stream>>>(Nb, We, Lg, cbm, sparse);

    select_kernel<<<NTOK, 256, 0, stream>>>(cbm, Lg, x, gamma, beta, Wenc, Wdict,
                                            sparse, recon);
}